// Round 6
// baseline (318.444 us; speedup 1.0000x reference)
//
#include <hip/hip_runtime.h>
#include <hip/hip_bf16.h>

#define IN_CH 128
#define D1 256      // HEADS*HID
#define HID 64
#define HEADS 4
#define SCAN_BLK 1024

typedef _Float16 h16;
typedef __attribute__((ext_vector_type(2))) _Float16 half2v;
typedef __attribute__((ext_vector_type(4))) _Float16 half4v;
typedef __attribute__((ext_vector_type(8))) _Float16 half8v;
typedef __attribute__((ext_vector_type(4))) float f32x4;

__device__ __forceinline__ float lrelu02(float v) { return v > 0.f ? v : 0.2f * v; }
__device__ __forceinline__ float lrelu001(float v) { return v > 0.f ? v : 0.01f * v; }

// ---- weight prep: w1t=[256][128] W1^T; w2t=[80][256] (W2^T + u2 rows 64/65, zero 66..79);
//      u1f=[8][128] f32 (W1@a_src1 heads 0..3, W1@a_dst1 heads 0..3) ----
__global__ __launch_bounds__(256) void prep_weights(const float* __restrict__ W1,
                                                    const float* __restrict__ W2,
                                                    const float* __restrict__ a_src1,
                                                    const float* __restrict__ a_dst1,
                                                    const float* __restrict__ a_src2,
                                                    const float* __restrict__ a_dst2,
                                                    h16* __restrict__ w1t,
                                                    h16* __restrict__ w2t,
                                                    float* __restrict__ u1f) {
    const int t = threadIdx.x;
    if (blockIdx.x == 0) {
        for (int k = 0; k < IN_CH; ++k) w1t[t * IN_CH + k] = (h16)W1[k * D1 + t];
    } else if (blockIdx.x == 1) {
        if (t < HID)
            for (int k = 0; k < D1; ++k) w2t[t * D1 + k] = (h16)W2[k * HID + t];
        for (int i = t; i < 14 * D1; i += 256) w2t[66 * D1 + i] = (h16)0.f;
    } else if (blockIdx.x == 2) {
        // u1f: 8 vecs x 128 entries (f32)
        for (int o = t; o < 1024; o += 256) {
            int v = o >> 7, k = o & 127;
            int h = v & 3;
            const float* avec = (v >> 2) ? (a_dst1 + h * HID) : (a_src1 + h * HID);
            const float* wrow = W1 + k * D1 + h * HID;
            float s = 0.f;
            for (int c = 0; c < HID; ++c) s += wrow[c] * avec[c];
            u1f[v * IN_CH + k] = s;
        }
    } else {
        for (int o = t; o < 512; o += 256) {
            int v = o >> 8, k = o & 255;
            const float* avec = v ? a_dst2 : a_src2;
            const float* wrow = W2 + k * HID;
            float s = 0.f;
            for (int c = 0; c < HID; ++c) s += wrow[c] * avec[c];
            w2t[(64 + v) * D1 + k] = (h16)s;
        }
    }
}

// ---- castx_row: wave per row; x->fp16, and asadx[row][8] = x_row @ u1f ----
__global__ __launch_bounds__(256) void castx_row(const float* __restrict__ x,
                                                 const float* __restrict__ u1f,
                                                 h16* __restrict__ xh,
                                                 float* __restrict__ asadx, int n) {
    const int lane = threadIdx.x & 63;
    const int row = (blockIdx.x * 256 + threadIdx.x) >> 6;
    if (row >= n) return;
    float2 xv = *(const float2*)&x[(size_t)row * IN_CH + lane * 2];
    half2v o; o.x = (h16)xv.x; o.y = (h16)xv.y;
    *(half2v*)&xh[(size_t)row * IN_CH + lane * 2] = o;
    float d0, d1, d2, d3, d4, d5, d6, d7;
    {
        const float* u = u1f + lane * 2;
        d0 = xv.x * u[0 * IN_CH] + xv.y * u[0 * IN_CH + 1];
        d1 = xv.x * u[1 * IN_CH] + xv.y * u[1 * IN_CH + 1];
        d2 = xv.x * u[2 * IN_CH] + xv.y * u[2 * IN_CH + 1];
        d3 = xv.x * u[3 * IN_CH] + xv.y * u[3 * IN_CH + 1];
        d4 = xv.x * u[4 * IN_CH] + xv.y * u[4 * IN_CH + 1];
        d5 = xv.x * u[5 * IN_CH] + xv.y * u[5 * IN_CH + 1];
        d6 = xv.x * u[6 * IN_CH] + xv.y * u[6 * IN_CH + 1];
        d7 = xv.x * u[7 * IN_CH] + xv.y * u[7 * IN_CH + 1];
    }
    #pragma unroll
    for (int off = 1; off < 64; off <<= 1) {
        d0 += __shfl_xor(d0, off, 64); d1 += __shfl_xor(d1, off, 64);
        d2 += __shfl_xor(d2, off, 64); d3 += __shfl_xor(d3, off, 64);
        d4 += __shfl_xor(d4, off, 64); d5 += __shfl_xor(d5, off, 64);
        d6 += __shfl_xor(d6, off, 64); d7 += __shfl_xor(d7, off, 64);
    }
    if (lane < 8) {
        float v = d0;
        if (lane == 1) v = d1; else if (lane == 2) v = d2;
        else if (lane == 3) v = d3; else if (lane == 4) v = d4;
        else if (lane == 5) v = d5; else if (lane == 6) v = d6;
        else if (lane == 7) v = d7;
        asadx[(size_t)row * 8 + lane] = v;
    }
}

// ================= CSR build (by destination) =================
__global__ __launch_bounds__(256) void hist_kernel(const int* __restrict__ ei,
                                                   int* __restrict__ cnt, int nE) {
    int e = blockIdx.x * 256 + threadIdx.x;
    if (e >= nE) return;
    atomicAdd(&cnt[ei[nE + e]], 1);
}

__global__ __launch_bounds__(256) void scan1_kernel(const int* __restrict__ cnt,
                                                    int* __restrict__ pre,
                                                    int* __restrict__ blockSums, int n) {
    __shared__ int lds[256];
    const int t = threadIdx.x;
    const int base = blockIdx.x * SCAN_BLK + t * 4;
    int v0 = 0, v1 = 0, v2 = 0, v3 = 0;
    if (base + 0 < n) v0 = cnt[base + 0];
    if (base + 1 < n) v1 = cnt[base + 1];
    if (base + 2 < n) v2 = cnt[base + 2];
    if (base + 3 < n) v3 = cnt[base + 3];
    int s = v0 + v1 + v2 + v3;
    lds[t] = s;
    __syncthreads();
    for (int off = 1; off < 256; off <<= 1) {
        int x = 0;
        if (t >= off) x = lds[t - off];
        __syncthreads();
        if (t >= off) lds[t] += x;
        __syncthreads();
    }
    int excl = lds[t] - s;
    if (t == 255) blockSums[blockIdx.x] = lds[255];
    if (base + 0 < n) pre[base + 0] = excl;
    if (base + 1 < n) pre[base + 1] = excl + v0;
    if (base + 2 < n) pre[base + 2] = excl + v0 + v1;
    if (base + 3 < n) pre[base + 3] = excl + v0 + v1 + v2;
}

__global__ void scan2_kernel(int* __restrict__ blockSums, int nb) {
    if (threadIdx.x == 0 && blockIdx.x == 0) {
        int acc = 0;
        for (int i = 0; i < nb; ++i) { int v = blockSums[i]; blockSums[i] = acc; acc += v; }
    }
}

__global__ __launch_bounds__(256) void scan3_kernel(int* __restrict__ pre,
                                                    const int* __restrict__ blockSums,
                                                    int* __restrict__ cursor, int n, int nE) {
    int i = blockIdx.x * 256 + threadIdx.x;
    if (i < n) {
        int v = pre[i] + blockSums[i / SCAN_BLK];
        pre[i] = v;
        cursor[i] = v;
    }
    if (i == 0) pre[n] = nE;
}

__global__ __launch_bounds__(256) void scatter_kernel(const int* __restrict__ ei,
                                                      int* __restrict__ cursor,
                                                      int* __restrict__ srcIdx,
                                                      int* __restrict__ dstIdx, int nE) {
    int e = blockIdx.x * 256 + threadIdx.x;
    if (e >= nE) return;
    int src = ei[e];
    int dst = ei[nE + e];
    int pos = atomicAdd(&cursor[dst], 1);
    srcIdx[pos] = src;
    dstIdx[pos] = dst;
}

// ---- edge weights (CSR order), fp16 ----
__global__ __launch_bounds__(256) void ewt1_kernel(const int* __restrict__ srcIdx,
                                                   const int* __restrict__ dstIdx,
                                                   const float* __restrict__ asadx,
                                                   h16* __restrict__ wE1, int nE4) {
    int t = blockIdx.x * 256 + threadIdx.x;
    if (t >= nE4) return;
    int j = t >> 2, h = t & 3;
    int s = srcIdx[j], d = dstIdx[j];
    wE1[t] = (h16)expf(lrelu02(asadx[(size_t)s * 8 + h] + asadx[(size_t)d * 8 + 4 + h]));
}

__global__ __launch_bounds__(256) void ewt2_kernel(const int* __restrict__ srcIdx,
                                                   const int* __restrict__ dstIdx,
                                                   const float* __restrict__ asad2,
                                                   h16* __restrict__ wE2, int nE) {
    int j = blockIdx.x * 256 + threadIdx.x;
    if (j >= nE) return;
    int s = srcIdx[j], d = dstIdx[j];
    wE2[j] = (h16)expf(lrelu02(asad2[(size_t)s * 2] + asad2[(size_t)d * 2 + 1]));
}

// ---- gatherx: wave per dst; aggregate x rows (4 heads), normalize, write aggx fp16 ----
__global__ __launch_bounds__(256) void gatherx_kernel(const h16* __restrict__ xh,
                                                      const float* __restrict__ asadx,
                                                      const h16* __restrict__ wE1,
                                                      const int* __restrict__ rowStart,
                                                      const int* __restrict__ srcIdx,
                                                      h16* __restrict__ aggx,
                                                      int n, int npad) {
    const int lane = threadIdx.x & 63;
    const int node = (blockIdx.x * 256 + threadIdx.x) >> 6;
    if (node >= npad) return;
    const size_t obase = (size_t)node * 512;   // [node][4][128] halfs
    if (node >= n) {                            // zero pad rows for MFMA
        half8v z = {};
        *(half8v*)&aggx[obase + lane * 8] = z;
        return;
    }
    // self-loop weights
    float4 asv = *(const float4*)&asadx[(size_t)node * 8];
    float4 adv = *(const float4*)&asadx[(size_t)node * 8 + 4];
    float w0 = expf(lrelu02(asv.x + adv.x));
    float w1 = expf(lrelu02(asv.y + adv.y));
    float w2 = expf(lrelu02(asv.z + adv.z));
    float w3 = expf(lrelu02(asv.w + adv.w));
    half2v sx = *(const half2v*)&xh[(size_t)node * IN_CH + lane * 2];
    float xa = (float)sx.x, xb = (float)sx.y;
    float a0x = w0 * xa, a0y = w0 * xb;
    float a1x = w1 * xa, a1y = w1 * xb;
    float a2x = w2 * xa, a2y = w2 * xb;
    float a3x = w3 * xa, a3y = w3 * xb;
    float d0 = w0, d1 = w1, d2 = w2, d3 = w3;
    const int beg = rowStart[node], end = rowStart[node + 1];
    int j = beg;
    for (; j + 3 < end; j += 4) {
        int s0 = srcIdx[j + 0];
        int s1 = srcIdx[j + 1];
        int s2 = srcIdx[j + 2];
        int s3 = srcIdx[j + 3];
        half4v wv0 = *(const half4v*)&wE1[(size_t)(j + 0) * 4];
        half4v wv1 = *(const half4v*)&wE1[(size_t)(j + 1) * 4];
        half4v wv2 = *(const half4v*)&wE1[(size_t)(j + 2) * 4];
        half4v wv3 = *(const half4v*)&wE1[(size_t)(j + 3) * 4];
        half2v r0 = *(const half2v*)&xh[(size_t)s0 * IN_CH + lane * 2];
        half2v r1 = *(const half2v*)&xh[(size_t)s1 * IN_CH + lane * 2];
        half2v r2 = *(const half2v*)&xh[(size_t)s2 * IN_CH + lane * 2];
        half2v r3 = *(const half2v*)&xh[(size_t)s3 * IN_CH + lane * 2];
        #pragma unroll
        for (int q = 0; q < 4; ++q) {
            half4v wv = q == 0 ? wv0 : q == 1 ? wv1 : q == 2 ? wv2 : wv3;
            half2v rr = q == 0 ? r0 : q == 1 ? r1 : q == 2 ? r2 : r3;
            float e0 = (float)wv.x, e1 = (float)wv.y, e2 = (float)wv.z, e3 = (float)wv.w;
            float rx = (float)rr.x, ry = (float)rr.y;
            a0x = fmaf(rx, e0, a0x); a0y = fmaf(ry, e0, a0y);
            a1x = fmaf(rx, e1, a1x); a1y = fmaf(ry, e1, a1y);
            a2x = fmaf(rx, e2, a2x); a2y = fmaf(ry, e2, a2y);
            a3x = fmaf(rx, e3, a3x); a3y = fmaf(ry, e3, a3y);
            d0 += e0; d1 += e1; d2 += e2; d3 += e3;
        }
    }
    for (; j < end; ++j) {
        int s = srcIdx[j];
        half4v wv = *(const half4v*)&wE1[(size_t)j * 4];
        half2v rr = *(const half2v*)&xh[(size_t)s * IN_CH + lane * 2];
        float e0 = (float)wv.x, e1 = (float)wv.y, e2 = (float)wv.z, e3 = (float)wv.w;
        float rx = (float)rr.x, ry = (float)rr.y;
        a0x = fmaf(rx, e0, a0x); a0y = fmaf(ry, e0, a0y);
        a1x = fmaf(rx, e1, a1x); a1y = fmaf(ry, e1, a1y);
        a2x = fmaf(rx, e2, a2x); a2y = fmaf(ry, e2, a2y);
        a3x = fmaf(rx, e3, a3x); a3y = fmaf(ry, e3, a3y);
        d0 += e0; d1 += e1; d2 += e2; d3 += e3;
    }
    float i0 = 1.f / (d0 + 1e-16f), i1 = 1.f / (d1 + 1e-16f);
    float i2 = 1.f / (d2 + 1e-16f), i3 = 1.f / (d3 + 1e-16f);
    half2v o;
    o.x = (h16)(a0x * i0); o.y = (h16)(a0y * i0);
    *(half2v*)&aggx[obase + 0 * IN_CH + lane * 2] = o;
    o.x = (h16)(a1x * i1); o.y = (h16)(a1y * i1);
    *(half2v*)&aggx[obase + 1 * IN_CH + lane * 2] = o;
    o.x = (h16)(a2x * i2); o.y = (h16)(a2y * i2);
    *(half2v*)&aggx[obase + 2 * IN_CH + lane * 2] = o;
    o.x = (h16)(a3x * i3); o.y = (h16)(a3y * i3);
    *(half2v*)&aggx[obase + 3 * IN_CH + lane * 2] = o;
}

// ---- gemm1b: hmid[NP,256] = per-head (aggx[:,h,:] @ W1[:,h*64:..]) + b1 -> LN -> lrelu, fp16 ----
__global__ __launch_bounds__(256) void gemm1b_mfma(const h16* __restrict__ aggx,
                                                   const h16* __restrict__ w1t,
                                                   const float* __restrict__ b1,
                                                   const float* __restrict__ gamma,
                                                   const float* __restrict__ beta,
                                                   h16* __restrict__ hmid) {
    const int wave = threadIdx.x >> 6, lane = threadIdx.x & 63;
    const int r = lane & 15, ksel = lane >> 4;
    const int rowBase = blockIdx.x * 64 + wave * 16;
    f32x4 acc[16];
    #pragma unroll
    for (int ct = 0; ct < 16; ++ct) acc[ct] = (f32x4){0.f, 0.f, 0.f, 0.f};
    #pragma unroll
    for (int h = 0; h < 4; ++h) {
        const h16* arow = aggx + (size_t)(rowBase + r) * 512 + h * IN_CH + ksel * 8;
        half8v a[4];
        #pragma unroll
        for (int kk = 0; kk < 4; ++kk) a[kk] = *(const half8v*)(arow + kk * 32);
        #pragma unroll
        for (int c4 = 0; c4 < 4; ++c4) {
            const int ct = h * 4 + c4;
            const h16* wrow = w1t + (size_t)(ct * 16 + r) * IN_CH + ksel * 8;
            #pragma unroll
            for (int kk = 0; kk < 4; ++kk) {
                half8v b = *(const half8v*)(wrow + kk * 32);
                acc[ct] = __builtin_amdgcn_mfma_f32_16x16x32_f16(a[kk], b, acc[ct], 0, 0, 0);
            }
        }
    }
    // epilogue: +b1, LayerNorm over 256 cols (cols spread over 16 lanes x 16 ct), lrelu
    float sum[4] = {0.f, 0.f, 0.f, 0.f}, sq[4] = {0.f, 0.f, 0.f, 0.f};
    #pragma unroll
    for (int ct = 0; ct < 16; ++ct) {
        float bb = b1[ct * 16 + r];
        #pragma unroll
        for (int i = 0; i < 4; ++i) {
            float y = acc[ct][i] + bb;
            acc[ct][i] = y;
            sum[i] += y;
            sq[i] = fmaf(y, y, sq[i]);
        }
    }
    #pragma unroll
    for (int off = 1; off < 16; off <<= 1) {
        #pragma unroll
        for (int i = 0; i < 4; ++i) {
            sum[i] += __shfl_xor(sum[i], off, 64);
            sq[i] += __shfl_xor(sq[i], off, 64);
        }
    }
    float mu[4], rs[4];
    #pragma unroll
    for (int i = 0; i < 4; ++i) {
        mu[i] = sum[i] * (1.f / 256.f);
        float var = sq[i] * (1.f / 256.f) - mu[i] * mu[i];
        rs[i] = rsqrtf(var + 1e-5f);
    }
    #pragma unroll
    for (int ct = 0; ct < 16; ++ct) {
        float g = gamma[ct * 16 + r];
        float be = beta[ct * 16 + r];
        #pragma unroll
        for (int i = 0; i < 4; ++i) {
            float o = lrelu001((acc[ct][i] - mu[i]) * rs[i] * g + be);
            hmid[(size_t)(rowBase + ksel * 4 + i) * D1 + ct * 16 + r] = (h16)o;
        }
    }
}

// ---- gemm2: h2[N,64](fp16) + asad2[N,2] = hmid[NP,256] @ w2t ----
__global__ __launch_bounds__(256) void gemm2_mfma(const h16* __restrict__ hm,
                                                  const h16* __restrict__ w2t,
                                                  h16* __restrict__ h2,
                                                  float* __restrict__ asad2, int n) {
    const int wave = threadIdx.x >> 6, lane = threadIdx.x & 63;
    const int r = lane & 15, ksel = lane >> 4;
    const int rowBase = blockIdx.x * 64 + wave * 16;
    const h16* xrow = hm + (size_t)(rowBase + r) * D1 + ksel * 8;
    half8v a[8];
    #pragma unroll
    for (int kk = 0; kk < 8; ++kk) a[kk] = *(const half8v*)(xrow + kk * 32);
    f32x4 acc[5];
    #pragma unroll
    for (int ct = 0; ct < 5; ++ct) acc[ct] = (f32x4){0.f, 0.f, 0.f, 0.f};
    #pragma unroll
    for (int ct = 0; ct < 5; ++ct) {
        const h16* wrow = w2t + (size_t)(ct * 16 + r) * D1 + ksel * 8;
        #pragma unroll
        for (int kk = 0; kk < 8; ++kk) {
            half8v b = *(const half8v*)(wrow + kk * 32);
            acc[ct] = __builtin_amdgcn_mfma_f32_16x16x32_f16(a[kk], b, acc[ct], 0, 0, 0);
        }
    }
    #pragma unroll
    for (int i = 0; i < 4; ++i) {
        int row = rowBase + ksel * 4 + i;
        if (row < n) {
            #pragma unroll
            for (int ct = 0; ct < 4; ++ct)
                h2[(size_t)row * HID + ct * 16 + r] = (h16)acc[ct][i];
            if (r < 2) asad2[(size_t)row * 2 + r] = acc[4][i];
        }
    }
}

// ---- gather2: wave per dst node (1 head x 64 ch) ----
__global__ __launch_bounds__(256) void gather2_kernel(const h16* __restrict__ h2,
                                                      const float* __restrict__ asad2,
                                                      const h16* __restrict__ wE2,
                                                      const int* __restrict__ rowStart,
                                                      const int* __restrict__ srcIdx,
                                                      const float* __restrict__ b2,
                                                      float* __restrict__ out, int n) {
    const int lane = threadIdx.x & 63;
    const int node = (blockIdx.x * 256 + threadIdx.x) >> 6;
    if (node >= n) return;
    const float w = expf(lrelu02(asad2[(size_t)node * 2] + asad2[(size_t)node * 2 + 1]));
    float acc = (float)h2[(size_t)node * HID + lane] * w;
    float den = w;
    const int beg = rowStart[node], end = rowStart[node + 1];
    int j = beg;
    for (; j + 7 < end; j += 8) {
        float wv[8]; float vv[8];
        #pragma unroll
        for (int q = 0; q < 8; ++q) {
            int s = srcIdx[j + q];
            wv[q] = (float)wE2[j + q];
            vv[q] = (float)h2[(size_t)s * HID + lane];
        }
        #pragma unroll
        for (int q = 0; q < 8; ++q) { acc = fmaf(vv[q], wv[q], acc); den += wv[q]; }
    }
    for (; j < end; ++j) {
        int s = srcIdx[j];
        float wj = (float)wE2[j];
        acc = fmaf((float)h2[(size_t)s * HID + lane], wj, acc);
        den += wj;
    }
    out[(size_t)node * HID + lane] = acc / (den + 1e-16f) + b2[lane];
}

extern "C" void kernel_launch(void* const* d_in, const int* in_sizes, int n_in,
                              void* d_out, int out_size, void* d_ws, size_t ws_size,
                              hipStream_t stream) {
    const float* x      = (const float*)d_in[0];
    const int*   ei     = (const int*)d_in[1];
    const float* W1     = (const float*)d_in[2];
    const float* a_src1 = (const float*)d_in[3];
    const float* a_dst1 = (const float*)d_in[4];
    const float* b1     = (const float*)d_in[5];
    const float* gamma  = (const float*)d_in[6];
    const float* beta   = (const float*)d_in[7];
    const float* W2     = (const float*)d_in[8];
    const float* a_src2 = (const float*)d_in[9];
    const float* a_dst2 = (const float*)d_in[10];
    const float* b2     = (const float*)d_in[11];
    float* out = (float*)d_out;

    const int N = in_sizes[0] / IN_CH;
    const int E = in_sizes[1] / 2;
    const int NP = (N + 63) & ~63;          // row-pad for 64-row MFMA tiles

    // workspace layout (float slots)
    float* ws = (float*)d_ws;
    size_t off = 0;
    h16*   xh   = (h16*)(ws + off); off += (size_t)64 * N;     // [N][128] halfs
    size_t aggx_off = off;
    h16*   aggx = (h16*)(ws + off); off += (size_t)256 * NP;   // [NP][4][128] halfs
    h16*   hmid = (h16*)(ws + off); off += (size_t)128 * NP;   // [NP][256] halfs
    float* asadx= ws + off;         off += (size_t)8 * N;      // [N][8]
    h16*   wE1  = (h16*)(ws + off); off += (size_t)2 * E;      // [E][4] halfs
    int* srcIdx    = (int*)(ws + off); off += E;
    int* dstIdx    = (int*)(ws + off); off += E;
    int* rowStart  = (int*)(ws + off); off += N + 1;
    int* cursor    = (int*)(ws + off); off += N;
    int* blockSums = (int*)(ws + off); off += 64;
    h16* w1t = (h16*)(ws + off); off += 16384;                 // [256][128] halfs
    h16* w2t = (h16*)(ws + off); off += 10240;                 // [80][256] halfs
    float* u1f = ws + off;       off += 1024;                  // [8][128]
    // overlays in dead aggx region (aggx unused after gemm1b)
    h16*   h2    = (h16*)(ws + aggx_off);                      // [N][64] halfs = 32N fl
    float* asad2 = ws + aggx_off + (size_t)32 * N;             // 2N fl
    h16*   wE2   = (h16*)(ws + aggx_off + (size_t)34 * N);     // E halfs

    const int nodeBlocks  = (N + 3) / 4;
    const int nodeBlocksP = (NP + 3) / 4;
    const int nThreadBlocksE = (E + 255) / 256;
    const int scanBlocks = (N + SCAN_BLK - 1) / SCAN_BLK;

    // prep + cast/asad
    prep_weights<<<4, 256, 0, stream>>>(W1, W2, a_src1, a_dst1, a_src2, a_dst2,
                                        w1t, w2t, u1f);
    castx_row<<<nodeBlocks, 256, 0, stream>>>(x, u1f, xh, asadx, N);

    // CSR build (by destination)
    hipMemsetAsync(cursor, 0, (size_t)N * 4, stream);
    hist_kernel<<<nThreadBlocksE, 256, 0, stream>>>(ei, cursor, E);
    scan1_kernel<<<scanBlocks, 256, 0, stream>>>(cursor, rowStart, blockSums, N);
    scan2_kernel<<<1, 64, 0, stream>>>(blockSums, scanBlocks);
    scan3_kernel<<<(N + 255) / 256, 256, 0, stream>>>(rowStart, blockSums, cursor, N, E);
    scatter_kernel<<<nThreadBlocksE, 256, 0, stream>>>(ei, cursor, srcIdx, dstIdx, E);

    // layer 1: x-space aggregation, then projected GEMM with fused LN
    ewt1_kernel<<<(4 * E + 255) / 256, 256, 0, stream>>>(srcIdx, dstIdx, asadx, wE1, 4 * E);
    gatherx_kernel<<<nodeBlocksP, 256, 0, stream>>>(xh, asadx, wE1, rowStart, srcIdx,
                                                    aggx, N, NP);
    gemm1b_mfma<<<NP / 64, 256, 0, stream>>>(aggx, w1t, b1, gamma, beta, hmid);

    // layer 2
    gemm2_mfma<<<NP / 64, 256, 0, stream>>>(hmid, w2t, h2, asad2, N);
    ewt2_kernel<<<nThreadBlocksE, 256, 0, stream>>>(srcIdx, dstIdx, asad2, wE2, E);
    gather2_kernel<<<nodeBlocks, 256, 0, stream>>>(h2, asad2, wE2, rowStart, srcIdx,
                                                   b2, out, N);
}

// Round 7
// 284.331 us; speedup vs baseline: 1.1200x; 1.1200x over previous
//
#include <hip/hip_runtime.h>
#include <hip/hip_bf16.h>

#define IN_CH 128
#define D1 256      // HEADS*HID
#define HID 64
#define HEADS 4
#define SCAN_BLK 1024

typedef _Float16 h16;
typedef __attribute__((ext_vector_type(4))) _Float16 half4v;
typedef __attribute__((ext_vector_type(8))) _Float16 half8v;
typedef __attribute__((ext_vector_type(4))) float f32x4;

__device__ __forceinline__ float lrelu02(float v) { return v > 0.f ? v : 0.2f * v; }
__device__ __forceinline__ float lrelu001(float v) { return v > 0.f ? v : 0.01f * v; }

// ---- setup: prep weights (blocks 0..3) | cast x->fp16 (castBlocks) | hist (rest) ----
// w1t: [272][128] rows 0..255=W1^T, 256..263=u1 (4 src + 4 dst heads), 264..271=0
// w2t: [80][256]  rows 0..63=W2^T, 64/65=u2 (src,dst), 66..79=0
__global__ __launch_bounds__(256) void setup_kernel(const float* __restrict__ x,
                                                    const float* __restrict__ W1,
                                                    const float* __restrict__ W2,
                                                    const float* __restrict__ a_src1,
                                                    const float* __restrict__ a_dst1,
                                                    const float* __restrict__ a_src2,
                                                    const float* __restrict__ a_dst2,
                                                    const int* __restrict__ ei,
                                                    int* __restrict__ cnt,
                                                    h16* __restrict__ xh,
                                                    h16* __restrict__ w1t,
                                                    h16* __restrict__ w2t,
                                                    long xtotal, long xvalid,
                                                    int nE, int castBlocks) {
    const int b = blockIdx.x;
    const int t = threadIdx.x;
    if (b == 0) {
        for (int k = 0; k < IN_CH; ++k) w1t[t * IN_CH + k] = (h16)W1[k * D1 + t];
    } else if (b == 1) {
        if (t < HID)
            for (int k = 0; k < D1; ++k) w2t[t * D1 + k] = (h16)W2[k * HID + t];
        for (int i = t; i < 14 * D1; i += 256) w2t[66 * D1 + i] = (h16)0.f;
    } else if (b == 2) {
        for (int o = t; o < 1024; o += 256) {
            int v = o >> 7, k = o & 127;
            int h = v & 3;
            const float* avec = (v >> 2) ? (a_dst1 + h * HID) : (a_src1 + h * HID);
            const float* wrow = W1 + k * D1 + h * HID;
            float s = 0.f;
            for (int c = 0; c < HID; ++c) s += wrow[c] * avec[c];
            w1t[(256 + v) * IN_CH + k] = (h16)s;
            w1t[(264 + v) * IN_CH + k] = (h16)0.f;
        }
    } else if (b == 3) {
        for (int o = t; o < 512; o += 256) {
            int v = o >> 8, k = o & 255;
            const float* avec = v ? a_dst2 : a_src2;
            const float* wrow = W2 + k * HID;
            float s = 0.f;
            for (int c = 0; c < HID; ++c) s += wrow[c] * avec[c];
            w2t[(64 + v) * D1 + k] = (h16)s;
        }
    } else if (b < 4 + castBlocks) {
        long i = ((long)(b - 4) * 256 + t) * 4;
        if (i < xtotal) {
            float4 v = make_float4(0.f, 0.f, 0.f, 0.f);
            if (i < xvalid) v = *(const float4*)&x[i];
            half4v o; o.x = (h16)v.x; o.y = (h16)v.y; o.z = (h16)v.z; o.w = (h16)v.w;
            *(half4v*)&xh[i] = o;
        }
    } else {
        int e = (b - 4 - castBlocks) * 256 + t;
        if (e < nE) atomicAdd(&cnt[ei[nE + e]], 1);
    }
}

// ---- scan1: per-block exclusive scan (1024 elems), block totals out ----
__global__ __launch_bounds__(256) void scan1_kernel(const int* __restrict__ cnt,
                                                    int* __restrict__ pre,
                                                    int* __restrict__ blockSums, int n) {
    __shared__ int lds[256];
    const int t = threadIdx.x;
    const int base = blockIdx.x * SCAN_BLK + t * 4;
    int v0 = 0, v1 = 0, v2 = 0, v3 = 0;
    if (base + 0 < n) v0 = cnt[base + 0];
    if (base + 1 < n) v1 = cnt[base + 1];
    if (base + 2 < n) v2 = cnt[base + 2];
    if (base + 3 < n) v3 = cnt[base + 3];
    int s = v0 + v1 + v2 + v3;
    lds[t] = s;
    __syncthreads();
    for (int off = 1; off < 256; off <<= 1) {
        int x = 0;
        if (t >= off) x = lds[t - off];
        __syncthreads();
        if (t >= off) lds[t] += x;
        __syncthreads();
    }
    int excl = lds[t] - s;
    if (t == 255) blockSums[blockIdx.x] = lds[255];
    if (base + 0 < n) pre[base + 0] = excl;
    if (base + 1 < n) pre[base + 1] = excl + v0;
    if (base + 2 < n) pre[base + 2] = excl + v0 + v1;
    if (base + 3 < n) pre[base + 3] = excl + v0 + v1 + v2;
}

// ---- scan23: add block offsets (wave-parallel sum of blockSums[0..b)) ----
__global__ __launch_bounds__(256) void scan23_kernel(int* __restrict__ pre,
                                                     const int* __restrict__ blockSums,
                                                     int* __restrict__ cursor,
                                                     int n, int nE, int nb) {
    __shared__ int soff_s;
    const int t = threadIdx.x;
    if (t < 64) {
        int v = (t < blockIdx.x && t < nb) ? blockSums[t] : 0;   // nb <= 64
        #pragma unroll
        for (int off = 1; off < 64; off <<= 1) v += __shfl_xor(v, off, 64);
        if (t == 0) soff_s = v;
    }
    __syncthreads();
    const int soff = soff_s;
    const int base = blockIdx.x * SCAN_BLK + t * 4;
    #pragma unroll
    for (int q = 0; q < 4; ++q) {
        int i = base + q;
        if (i < n) {
            int v = pre[i] + soff;
            pre[i] = v;
            cursor[i] = v;
        }
    }
    if (blockIdx.x == 0 && t == 0) pre[n] = nE;
}

__global__ __launch_bounds__(256) void scatter_kernel(const int* __restrict__ ei,
                                                      int* __restrict__ cursor,
                                                      int* __restrict__ srcIdx,
                                                      int* __restrict__ dstIdx, int nE) {
    int e = blockIdx.x * 256 + threadIdx.x;
    if (e >= nE) return;
    int src = ei[e];
    int dst = ei[nE + e];
    int pos = atomicAdd(&cursor[dst], 1);
    srcIdx[pos] = src;
    dstIdx[pos] = dst;
}

// ---- MFMA GEMM1: h1[N,256](fp16) + asad[N,8] = xh[NP,128] @ w1t ----
__global__ __launch_bounds__(256) void gemm1_mfma(const h16* __restrict__ xh,
                                                  const h16* __restrict__ w1t,
                                                  h16* __restrict__ h1,
                                                  float* __restrict__ asad, int n) {
    const int wave = threadIdx.x >> 6, lane = threadIdx.x & 63;
    const int r = lane & 15, ksel = lane >> 4;
    const int rowBase = blockIdx.x * 64 + wave * 16;
    const h16* xrow = xh + (size_t)(rowBase + r) * IN_CH + ksel * 8;
    half8v a[4];
    #pragma unroll
    for (int kk = 0; kk < 4; ++kk) a[kk] = *(const half8v*)(xrow + kk * 32);
    f32x4 acc[17];
    #pragma unroll
    for (int ct = 0; ct < 17; ++ct) acc[ct] = (f32x4){0.f, 0.f, 0.f, 0.f};
    #pragma unroll
    for (int ct = 0; ct < 17; ++ct) {
        const h16* wrow = w1t + (size_t)(ct * 16 + r) * IN_CH + ksel * 8;
        #pragma unroll
        for (int kk = 0; kk < 4; ++kk) {
            half8v b = *(const half8v*)(wrow + kk * 32);
            acc[ct] = __builtin_amdgcn_mfma_f32_16x16x32_f16(a[kk], b, acc[ct], 0, 0, 0);
        }
    }
    #pragma unroll
    for (int i = 0; i < 4; ++i) {
        int row = rowBase + ksel * 4 + i;
        if (row < n) {
            #pragma unroll
            for (int ct = 0; ct < 16; ++ct)
                h1[(size_t)row * D1 + ct * 16 + r] = (h16)acc[ct][i];
            if (r < 8) asad[(size_t)row * 8 + r] = acc[16][i];
        }
    }
}

// ---- MFMA GEMM2: h2[N,64](fp16) + asad2[N,2] = hmid[NP,256] @ w2t ----
__global__ __launch_bounds__(256) void gemm2_mfma(const h16* __restrict__ hm,
                                                  const h16* __restrict__ w2t,
                                                  h16* __restrict__ h2,
                                                  float* __restrict__ asad2, int n) {
    const int wave = threadIdx.x >> 6, lane = threadIdx.x & 63;
    const int r = lane & 15, ksel = lane >> 4;
    const int rowBase = blockIdx.x * 64 + wave * 16;
    const h16* xrow = hm + (size_t)(rowBase + r) * D1 + ksel * 8;
    half8v a[8];
    #pragma unroll
    for (int kk = 0; kk < 8; ++kk) a[kk] = *(const half8v*)(xrow + kk * 32);
    f32x4 acc[5];
    #pragma unroll
    for (int ct = 0; ct < 5; ++ct) acc[ct] = (f32x4){0.f, 0.f, 0.f, 0.f};
    #pragma unroll
    for (int ct = 0; ct < 5; ++ct) {
        const h16* wrow = w2t + (size_t)(ct * 16 + r) * D1 + ksel * 8;
        #pragma unroll
        for (int kk = 0; kk < 8; ++kk) {
            half8v b = *(const half8v*)(wrow + kk * 32);
            acc[ct] = __builtin_amdgcn_mfma_f32_16x16x32_f16(a[kk], b, acc[ct], 0, 0, 0);
        }
    }
    #pragma unroll
    for (int i = 0; i < 4; ++i) {
        int row = rowBase + ksel * 4 + i;
        if (row < n) {
            #pragma unroll
            for (int ct = 0; ct < 4; ++ct)
                h2[(size_t)row * HID + ct * 16 + r] = (h16)acc[ct][i];
            if (r < 2) asad2[(size_t)row * 2 + r] = acc[4][i];
        }
    }
}

// ---- edge weights (CSR order), fp16 ----
__global__ __launch_bounds__(256) void ewt1_kernel(const int* __restrict__ srcIdx,
                                                   const int* __restrict__ dstIdx,
                                                   const float* __restrict__ asad,
                                                   h16* __restrict__ wE1, int nE4) {
    int t = blockIdx.x * 256 + threadIdx.x;
    if (t >= nE4) return;
    int j = t >> 2, h = t & 3;
    int s = srcIdx[j], d = dstIdx[j];
    wE1[t] = (h16)expf(lrelu02(asad[(size_t)s * 8 + h] + asad[(size_t)d * 8 + 4 + h]));
}

__global__ __launch_bounds__(256) void ewt2_kernel(const int* __restrict__ srcIdx,
                                                   const int* __restrict__ dstIdx,
                                                   const float* __restrict__ asad2,
                                                   h16* __restrict__ wE2, int nE) {
    int j = blockIdx.x * 256 + threadIdx.x;
    if (j >= nE) return;
    int s = srcIdx[j], d = dstIdx[j];
    wE2[j] = (h16)expf(lrelu02(asad2[(size_t)s * 2] + asad2[(size_t)d * 2 + 1]));
}

// ---- gather1: wave per dst node; h1-space aggregate; fused bias+LN+lrelu; fp16 out ----
__global__ __launch_bounds__(256) void gather1_kernel(const h16* __restrict__ h1,
                                                      const float* __restrict__ asad,
                                                      const h16* __restrict__ wE1,
                                                      const int* __restrict__ rowStart,
                                                      const int* __restrict__ srcIdx,
                                                      const float* __restrict__ b1,
                                                      const float* __restrict__ gamma,
                                                      const float* __restrict__ beta,
                                                      h16* __restrict__ hmid, int n, int npad) {
    const int lane = threadIdx.x & 63;
    const int node = (blockIdx.x * 256 + threadIdx.x) >> 6;
    if (node >= npad) return;
    if (node >= n) {            // zero pad rows (gemm2 reads them)
        half4v z = {(h16)0.f, (h16)0.f, (h16)0.f, (h16)0.f};
        *(half4v*)&hmid[(size_t)node * D1 + lane * 4] = z;
        return;
    }
    const int hh = lane >> 4;
    const float w = expf(lrelu02(asad[(size_t)node * 8 + hh] +
                                 asad[(size_t)node * 8 + 4 + hh]));  // self-loop
    half4v sv = *(const half4v*)&h1[(size_t)node * D1 + lane * 4];
    float4 acc = make_float4((float)sv.x * w, (float)sv.y * w,
                             (float)sv.z * w, (float)sv.w * w);
    float den = w;
    const int beg = rowStart[node], end = rowStart[node + 1];
    int j = beg;
    for (; j + 7 < end; j += 8) {
        int sI[8]; float wv[8]; half4v rv[8];
        #pragma unroll
        for (int q = 0; q < 8; ++q) sI[q] = srcIdx[j + q];
        #pragma unroll
        for (int q = 0; q < 8; ++q) wv[q] = (float)wE1[(size_t)(j + q) * 4 + hh];
        #pragma unroll
        for (int q = 0; q < 8; ++q) rv[q] = *(const half4v*)&h1[(size_t)sI[q] * D1 + lane * 4];
        #pragma unroll
        for (int q = 0; q < 8; ++q) {
            acc.x = fmaf((float)rv[q].x, wv[q], acc.x);
            acc.y = fmaf((float)rv[q].y, wv[q], acc.y);
            acc.z = fmaf((float)rv[q].z, wv[q], acc.z);
            acc.w = fmaf((float)rv[q].w, wv[q], acc.w);
            den += wv[q];
        }
    }
    for (; j + 3 < end; j += 4) {
        int sI[4]; float wv[4]; half4v rv[4];
        #pragma unroll
        for (int q = 0; q < 4; ++q) sI[q] = srcIdx[j + q];
        #pragma unroll
        for (int q = 0; q < 4; ++q) wv[q] = (float)wE1[(size_t)(j + q) * 4 + hh];
        #pragma unroll
        for (int q = 0; q < 4; ++q) rv[q] = *(const half4v*)&h1[(size_t)sI[q] * D1 + lane * 4];
        #pragma unroll
        for (int q = 0; q < 4; ++q) {
            acc.x = fmaf((float)rv[q].x, wv[q], acc.x);
            acc.y = fmaf((float)rv[q].y, wv[q], acc.y);
            acc.z = fmaf((float)rv[q].z, wv[q], acc.z);
            acc.w = fmaf((float)rv[q].w, wv[q], acc.w);
            den += wv[q];
        }
    }
    for (; j < end; ++j) {
        int s = srcIdx[j];
        float wj = (float)wE1[(size_t)j * 4 + hh];
        half4v xv = *(const half4v*)&h1[(size_t)s * D1 + lane * 4];
        acc.x = fmaf((float)xv.x, wj, acc.x);
        acc.y = fmaf((float)xv.y, wj, acc.y);
        acc.z = fmaf((float)xv.z, wj, acc.z);
        acc.w = fmaf((float)xv.w, wj, acc.w);
        den += wj;
    }
    float inv = 1.f / (den + 1e-16f);
    float4 bv = *(const float4*)&b1[lane * 4];
    float4 y;
    y.x = acc.x * inv + bv.x; y.y = acc.y * inv + bv.y;
    y.z = acc.z * inv + bv.z; y.w = acc.w * inv + bv.w;
    float s = y.x + y.y + y.z + y.w;
    #pragma unroll
    for (int off = 1; off < 64; off <<= 1) s += __shfl_xor(s, off, 64);
    float mu = s * (1.f / 256.f);
    float4 dx;
    dx.x = y.x - mu; dx.y = y.y - mu; dx.z = y.z - mu; dx.w = y.w - mu;
    float sq = dx.x * dx.x + dx.y * dx.y + dx.z * dx.z + dx.w * dx.w;
    #pragma unroll
    for (int off = 1; off < 64; off <<= 1) sq += __shfl_xor(sq, off, 64);
    float rs = rsqrtf(sq * (1.f / 256.f) + 1e-5f);
    float4 g = *(const float4*)&gamma[lane * 4];
    float4 be = *(const float4*)&beta[lane * 4];
    half4v o;
    o.x = (h16)lrelu001(dx.x * rs * g.x + be.x);
    o.y = (h16)lrelu001(dx.y * rs * g.y + be.y);
    o.z = (h16)lrelu001(dx.z * rs * g.z + be.z);
    o.w = (h16)lrelu001(dx.w * rs * g.w + be.w);
    *(half4v*)&hmid[(size_t)node * D1 + lane * 4] = o;
}

// ---- gather2: wave per dst node (1 head x 64 ch) ----
__global__ __launch_bounds__(256) void gather2_kernel(const h16* __restrict__ h2,
                                                      const float* __restrict__ asad2,
                                                      const h16* __restrict__ wE2,
                                                      const int* __restrict__ rowStart,
                                                      const int* __restrict__ srcIdx,
                                                      const float* __restrict__ b2,
                                                      float* __restrict__ out, int n) {
    const int lane = threadIdx.x & 63;
    const int node = (blockIdx.x * 256 + threadIdx.x) >> 6;
    if (node >= n) return;
    const float w = expf(lrelu02(asad2[(size_t)node * 2] + asad2[(size_t)node * 2 + 1]));
    float acc = (float)h2[(size_t)node * HID + lane] * w;
    float den = w;
    const int beg = rowStart[node], end = rowStart[node + 1];
    int j = beg;
    for (; j + 7 < end; j += 8) {
        float wv[8]; float vv[8];
        #pragma unroll
        for (int q = 0; q < 8; ++q) {
            int s = srcIdx[j + q];
            wv[q] = (float)wE2[j + q];
            vv[q] = (float)h2[(size_t)s * HID + lane];
        }
        #pragma unroll
        for (int q = 0; q < 8; ++q) { acc = fmaf(vv[q], wv[q], acc); den += wv[q]; }
    }
    for (; j < end; ++j) {
        int s = srcIdx[j];
        float wj = (float)wE2[j];
        acc = fmaf((float)h2[(size_t)s * HID + lane], wj, acc);
        den += wj;
    }
    out[(size_t)node * HID + lane] = acc / (den + 1e-16f) + b2[lane];
}

extern "C" void kernel_launch(void* const* d_in, const int* in_sizes, int n_in,
                              void* d_out, int out_size, void* d_ws, size_t ws_size,
                              hipStream_t stream) {
    const float* x      = (const float*)d_in[0];
    const int*   ei     = (const int*)d_in[1];
    const float* W1     = (const float*)d_in[2];
    const float* a_src1 = (const float*)d_in[3];
    const float* a_dst1 = (const float*)d_in[4];
    const float* b1     = (const float*)d_in[5];
    const float* gamma  = (const float*)d_in[6];
    const float* beta   = (const float*)d_in[7];
    const float* W2     = (const float*)d_in[8];
    const float* a_src2 = (const float*)d_in[9];
    const float* a_dst2 = (const float*)d_in[10];
    const float* b2     = (const float*)d_in[11];
    float* out = (float*)d_out;

    const int N = in_sizes[0] / IN_CH;
    const int E = in_sizes[1] / 2;
    const int NP = (N + 63) & ~63;          // row-pad for 64-row MFMA tiles

    // workspace layout (float slots)
    float* ws = (float*)d_ws;
    size_t off = 0;
    h16*   xh   = (h16*)(ws + off); off += (size_t)64 * NP;    // [NP][128] halfs
    h16*   h1   = (h16*)(ws + off); off += (size_t)128 * N;    // [N][256] halfs
    h16*   hmid = (h16*)(ws + off); off += (size_t)128 * NP;   // [NP][256] halfs
    h16*   h2   = (h16*)(ws + off); off += (size_t)32 * N;     // [N][64] halfs
    float* asad = ws + off;         off += (size_t)8 * N;      // [N][8]
    float* asad2= ws + off;         off += (size_t)2 * N;      // [N][2]
    h16*   wE1  = (h16*)(ws + off); off += (size_t)2 * E;      // [E][4] halfs
    h16*   wE2  = (h16*)(ws + off); off += (E + 1) / 2;        // [E] halfs
    int* srcIdx    = (int*)(ws + off); off += E;
    int* dstIdx    = (int*)(ws + off); off += E;
    int* rowStart  = (int*)(ws + off); off += N + 1;
    int* cursor    = (int*)(ws + off); off += N;
    int* blockSums = (int*)(ws + off); off += 64;
    h16* w1t = (h16*)(ws + off); off += 17408;                 // [272][128] halfs
    h16* w2t = (h16*)(ws + off); off += 10240;                 // [80][256] halfs

    const int nodeBlocks  = (N + 3) / 4;
    const int nodeBlocksP = (NP + 3) / 4;
    const int nThreadBlocksE = (E + 255) / 256;
    const int scanBlocks = (N + SCAN_BLK - 1) / SCAN_BLK;      // <= 64 for N <= 65536
    const int castBlocks = (int)(((long)NP * IN_CH / 4 + 255) / 256);

    // CSR counters must be zero before hist (inside setup)
    hipMemsetAsync(cursor, 0, (size_t)N * 4, stream);
    setup_kernel<<<4 + castBlocks + nThreadBlocksE, 256, 0, stream>>>(
        x, W1, W2, a_src1, a_dst1, a_src2, a_dst2, ei, cursor,
        xh, w1t, w2t, (long)NP * IN_CH, (long)N * IN_CH, E, castBlocks);
    scan1_kernel<<<scanBlocks, 256, 0, stream>>>(cursor, rowStart, blockSums, N);
    scan23_kernel<<<scanBlocks, 256, 0, stream>>>(rowStart, blockSums, cursor, N, E, scanBlocks);
    scatter_kernel<<<nThreadBlocksE, 256, 0, stream>>>(ei, cursor, srcIdx, dstIdx, E);

    // layer 1
    gemm1_mfma<<<NP / 64, 256, 0, stream>>>(xh, w1t, h1, asad, N);
    ewt1_kernel<<<(4 * E + 255) / 256, 256, 0, stream>>>(srcIdx, dstIdx, asad, wE1, 4 * E);
    gather1_kernel<<<nodeBlocksP, 256, 0, stream>>>(h1, asad, wE1, rowStart, srcIdx,
                                                    b1, gamma, beta, hmid, N, NP);
    // layer 2
    gemm2_mfma<<<NP / 64, 256, 0, stream>>>(hmid, w2t, h2, asad2, N);
    ewt2_kernel<<<nThreadBlocksE, 256, 0, stream>>>(srcIdx, dstIdx, asad2, wE2, E);
    gather2_kernel<<<nodeBlocks, 256, 0, stream>>>(h2, asad2, wE2, rowStart, srcIdx,
                                                   b2, out, N);
}